// Round 1
// baseline (509.458 us; speedup 1.0000x reference)
//
#include <hip/hip_runtime.h>
#include <hip/hip_bf16.h>
#include <math.h>

#define NBAND 8
#define K1_THREADS 1024
#define CHUNK 512
#define HALO  192
#define TILE  16

struct Params {
  float lags[NBAND];
  float amps[NBAND];
  float a, c, kphi1, kphi2;
  int bandstart[NBAND];
  int nb[NBAND];
  int blkbase[NBAND + 1];
};

// ---------------- K0: params + zero accumulators ----------------
__global__ void k0_init(const float* __restrict__ lad, const float* __restrict__ lag,
                        const float* __restrict__ lkp, Params* __restrict__ P,
                        double* __restrict__ acc) {
  if (threadIdx.x == 0) {
    P->lags[0] = 0.f;
    P->amps[0] = 1.f;
    for (int j = 0; j < NBAND - 1; ++j) {
      P->lags[j + 1] = lag[j];
      P->amps[j + 1] = expf(lad[j]);
    }
    float a = expf(lkp[0]);
    float c = expf(lkp[1]);
    P->a = a;
    P->c = c;
    P->kphi1 = -c * 1.4426950408889634f;        // phi   = exp2(kphi1*dt)
    P->kphi2 = -2.f * c * 1.4426950408889634f;  // phi^2 = exp2(kphi2*dt)
    acc[0] = 0.0;
    acc[1] = 0.0;
  }
}

// ---------------- K1: per-block band histogram ----------------
__global__ void k1_hist(const int* __restrict__ band, int* __restrict__ cnt) {
  __shared__ int l[NBAND];
  int tid = threadIdx.x;
  if (tid < NBAND) l[tid] = 0;
  __syncthreads();
  int i = blockIdx.x * K1_THREADS + tid;
  atomicAdd(&l[band[i]], 1);
  __syncthreads();
  if (tid < NBAND) cnt[blockIdx.x * NBAND + tid] = l[tid];
}

// ---------------- K2: scan block counts -> per-(block,band) offsets ----------------
// 1 block, 1024 threads. band b = tid>>7, segment seg = tid&127, 32 blocks per thread.
__global__ void k2_scan(const int* __restrict__ cnt, int* __restrict__ boff,
                        Params* __restrict__ P, int nblk) {
  __shared__ int sd[1024];
  __shared__ int tot[NBAND], bstart[NBAND];
  int tid = threadIdx.x;
  int b = tid >> 7, seg = tid & 127;
  int per = nblk / 128;  // 32
  int blk0 = seg * per;
  int sum = 0;
  for (int u = 0; u < per; ++u) sum += cnt[(blk0 + u) * NBAND + b];
  int val = sum;
  sd[tid] = val;
  __syncthreads();
  for (int off = 1; off < 128; off <<= 1) {
    int yv = (seg >= off) ? sd[tid - off] : 0;
    __syncthreads();
    val += yv;
    sd[tid] = val;
    __syncthreads();
  }
  if (seg == 127) tot[b] = val;
  __syncthreads();
  if (tid == 0) {
    int g = 0;
    for (int bb = 0; bb < NBAND; ++bb) {
      bstart[bb] = g;
      P->bandstart[bb] = g;
      P->nb[bb] = tot[bb];
      g += tot[bb];
    }
    int s = 0;
    for (int bb = 0; bb < NBAND; ++bb) {
      P->blkbase[bb] = s;
      s += (tot[bb] + 255) / 256;
    }
    P->blkbase[NBAND] = s;
  }
  __syncthreads();
  int run = bstart[b] + (val - sum);  // band base + exclusive prefix of earlier segments
  for (int u = 0; u < per; ++u) {
    int idx = (blk0 + u) * NBAND + b;
    int x = cnt[idx];
    boff[idx] = run;
    run += x;
  }
}

// ---------------- K3: stable scatter into band-partitioned (value, index) ----------------
__global__ void k3_scatter(const float* __restrict__ t, const int* __restrict__ band,
                           const int* __restrict__ boff, const Params* __restrict__ P,
                           float* __restrict__ bt, int* __restrict__ bidx) {
  __shared__ int wc[16][NBAND];
  int tid = threadIdx.x;
  int i = blockIdx.x * K1_THREADS + tid;
  int b = band[i];
  float v = t[i] - P->lags[b];
  int lane = tid & 63, w = tid >> 6;
  int lower = 0;
  for (int bb = 0; bb < NBAND; ++bb) {
    unsigned long long m = __ballot(b == bb);
    if (lane == bb) wc[w][bb] = __popcll(m);
    if (b == bb) lower = __popcll(m & ((1ull << lane) - 1ull));
  }
  __syncthreads();
  int base = 0;
  for (int w2 = 0; w2 < w; ++w2) base += wc[w2][b];
  int pos = boff[blockIdx.x * NBAND + b] + base + lower;
  bt[pos] = v;
  bidx[pos] = i;
}

// ---------------- K4: 8-way-merge rank + build sorted float4(t,y,diag,amp) ----------------
__global__ void k4_rank(const float* __restrict__ bt, const int* __restrict__ bidx,
                        const float* __restrict__ y, const float* __restrict__ dg,
                        const Params* __restrict__ P, float4* __restrict__ out4) {
  __shared__ int bnd[7][2];
  __shared__ int sbs[NBAND], snb[NBAND];
  int tid = threadIdx.x;
  int bid = blockIdx.x;
  int total = P->blkbase[NBAND];
  if (bid >= total) return;
  if (tid < NBAND) {
    sbs[tid] = P->bandstart[tid];
    snb[tid] = P->nb[tid];
  }
  int b0 = 0;
  for (int b = 1; b < NBAND; ++b)
    if (bid >= P->blkbase[b]) b0 = b;
  int chunk = bid - P->blkbase[b0];
  __syncthreads();
  int q0 = chunk * 256;
  int bs0 = sbs[b0];
  int m = min(256, snb[b0] - q0);
  // bracket: threads 0..13 do the 7x2 global binary searches
  if (tid < 14) {
    int j = tid >> 1, which = tid & 1;
    int bo = j + (j >= b0);
    float v = bt[bs0 + q0 + (which ? (m - 1) : 0)];
    bool le = (bo < b0);  // key order (value, band)
    const float* p = bt + sbs[bo];
    int lo = 0, hi = snb[bo];
    while (lo < hi) {
      int mid = (lo + hi) >> 1;
      float w = p[mid];
      bool pr = le ? (w <= v) : (w < v);
      if (pr) lo = mid + 1; else hi = mid;
    }
    bnd[j][which] = lo;
  }
  __syncthreads();
  if (tid < m) {
    float v = bt[bs0 + q0 + tid];
    int idx = bidx[bs0 + q0 + tid];
    int rank = q0 + tid;
    int lo[7], hi[7], bs[7];
    bool le[7];
#pragma unroll
    for (int j = 0; j < 7; ++j) {
      int bo = j + (j >= b0);
      lo[j] = bnd[j][0];
      hi[j] = bnd[j][1];
      bs[j] = sbs[bo];
      le[j] = (bo < b0);
    }
    // 7 independent binary searches advanced in lockstep (latency overlap)
    bool any = true;
    while (any) {
      any = false;
#pragma unroll
      for (int j = 0; j < 7; ++j) {
        if (lo[j] < hi[j]) {
          int mid = (lo[j] + hi[j]) >> 1;
          float w = bt[bs[j] + mid];
          bool pr = le[j] ? (w <= v) : (w < v);
          if (pr) lo[j] = mid + 1; else hi[j] = mid;
          if (lo[j] < hi[j]) any = true;
        }
      }
    }
#pragma unroll
    for (int j = 0; j < 7; ++j) rank += lo[j];
    float yv = y[idx], dv = dg[idx];
    out4[rank] = make_float4(v, yv, dv, P->amps[b0]);
  }
}

// ---------------- K5: chunked celerite scan with halo warm-up ----------------
struct ScanState {
  float Sp, fp, tprev, s1, s2;
};

template <bool ACCUM>
__device__ __forceinline__ void step_one(float4 v, ScanState& st, float a, float k1c,
                                         float k2c) {
  float t = v.x, yv = v.y, d = v.z, amp = v.w;
  float dt = t - st.tprev;
  st.tprev = t;
  float e2 = __builtin_amdgcn_exp2f(k2c * dt);  // phi^2
  float e1 = __builtin_amdgcn_exp2f(k1c * dt);  // phi
  float U = a * amp;
  float aa2 = U * amp;        // a*amp^2 = U*V
  float Aa = d + aa2;         // diagonal A
  float c1 = d - aa2;         // A - 2UV
  float V2 = amp * amp;
  float x = e2 * st.Sp;       // S_n
  float D = fmaf(-(U * U), x, Aa);
  float r = __builtin_amdgcn_rcpf(D);
  float num = fmaf(c1, x, V2);
  st.Sp = num * r;            // Moebius form of S + D*W^2
  float f = e1 * st.fp;
  float z = fmaf(-U, f, yv);
  float Wn = fmaf(-U, x, amp);  // V - U*S
  float W = Wn * r;
  st.fp = fmaf(W, z, f);
  if (ACCUM) {
    st.s1 = fmaf(z * z, r, st.s1);
    st.s2 += __builtin_amdgcn_logf(D);  // log2(D)
  }
}

template <bool ACCUM>
__device__ __forceinline__ void run_range(const float4* __restrict__ q, long s, long e,
                                          ScanState& st, float a, float k1c, float k2c) {
  float4 A[TILE], B[TILE];
#pragma unroll
  for (int u = 0; u < TILE; ++u) A[u] = q[s + u];
  for (long tb = s; tb < e; tb += 2 * TILE) {
#pragma unroll
    for (int u = 0; u < TILE; ++u) B[u] = q[tb + TILE + u];
#pragma unroll
    for (int u = 0; u < TILE; ++u) step_one<ACCUM>(A[u], st, a, k1c, k2c);
#pragma unroll
    for (int u = 0; u < TILE; ++u) A[u] = q[tb + 2 * TILE + u];  // prefetch next
#pragma unroll
    for (int u = 0; u < TILE; ++u) step_one<ACCUM>(B[u], st, a, k1c, k2c);
  }
}

__global__ __launch_bounds__(64, 1) void k5_scan(const float4* __restrict__ q,
                                                 const Params* __restrict__ P,
                                                 double* __restrict__ acc) {
  int k = blockIdx.x * 64 + threadIdx.x;
  long base = (long)k * CHUNK;
  float a = P->a, k1c = P->kphi1, k2c = P->kphi2;
  ScanState st;
  st.Sp = 0.f;
  st.fp = 0.f;
  st.s1 = 0.f;
  st.s2 = 0.f;
  long s0 = (k == 0) ? base : (base - HALO);
  st.tprev = q[s0].x;  // first dt = 0 (matches reference prepend for k==0; fresh start otherwise)
  if (k > 0) run_range<false>(q, base - HALO, base, st, a, k1c, k2c);
  run_range<true>(q, base, base + CHUNK, st, a, k1c, k2c);
  float s1 = st.s1, s2 = st.s2;
#pragma unroll
  for (int off = 32; off > 0; off >>= 1) {
    s1 += __shfl_down(s1, off);
    s2 += __shfl_down(s2, off);
  }
  if (threadIdx.x == 0) {
    atomicAdd(&acc[0], (double)s1);
    atomicAdd(&acc[1], (double)s2);
  }
}

// ---------------- K6: finalize ----------------
__global__ void k6_final(const double* __restrict__ acc, float* __restrict__ out, long n) {
  // -logp = 0.5*(sum z^2/D + sum ln D + n*ln(2*pi)); acc[1] holds sum log2(D)
  double r = 0.5 * (acc[0] + acc[1] * 0.6931471805599453 +
                    (double)n * 1.8378770664093453);
  out[0] = (float)r;
}

extern "C" void kernel_launch(void* const* d_in, const int* in_sizes, int n_in,
                              void* d_out, int out_size, void* d_ws, size_t ws_size,
                              hipStream_t stream) {
  const float* t = (const float*)d_in[0];
  const int* band = (const int*)d_in[1];
  const float* y = (const float*)d_in[2];
  const float* dg = (const float*)d_in[3];
  const float* lad = (const float*)d_in[4];
  const float* lag = (const float*)d_in[5];
  const float* lkp = (const float*)d_in[6];
  float* out = (float*)d_out;
  long N = in_sizes[0];

  char* ws = (char*)d_ws;
  Params* P = (Params*)(ws + 0);
  double* acc = (double*)(ws + 1024);
  int* cnt = (int*)(ws + 8192);
  long nblk = N / K1_THREADS;  // 4096
  int* boff = (int*)(ws + 8192 + nblk * NBAND * 4);
  size_t off_bt = 524288;
  float* bt = (float*)(ws + off_bt);
  int* bidx = (int*)(ws + off_bt + (size_t)N * 4);
  float4* out4 = (float4*)(ws + off_bt + (size_t)N * 8);
  // total ws need: 524288 + N*4 + N*4 + N*16 + slack  (~101.2 MB for N=4.19M)

  k0_init<<<1, 64, 0, stream>>>(lad, lag, lkp, P, acc);
  k1_hist<<<(int)nblk, K1_THREADS, 0, stream>>>(band, cnt);
  k2_scan<<<1, 1024, 0, stream>>>(cnt, boff, P, (int)nblk);
  k3_scatter<<<(int)nblk, K1_THREADS, 0, stream>>>(t, band, boff, P, bt, bidx);
  long nb4 = N / 256 + NBAND;  // 16392 (a few blocks idle-exit)
  k4_rank<<<(int)nb4, 256, 0, stream>>>(bt, bidx, y, dg, P, out4);
  long T = N / CHUNK;  // 8192 scan threads
  k5_scan<<<(int)(T / 64), 64, 0, stream>>>(out4, P, acc);
  k6_final<<<1, 1, 0, stream>>>(acc, out, N);
}